// Round 2
// baseline (2762.941 us; speedup 1.0000x reference)
//
#include <hip/hip_runtime.h>

#define TPB 256
#define TC  128          // h3 output positions per chunk
#define NCH 8            // ceil(988 / TC)

// compile-time LDS strides (max lengths at tc=128)
#define SX 140           // x chunk length  (tc+12)
#define S1 136           // h1 length       (tc+8)
#define S2 132           // h2 length       (tc+4)
#define S3 128           // h3 length       (tc)
#define SM 140           // m buffer length (stage Lo+4, max = tc+12)

// wbuf layout: [0..500) conv k | [500..510) conv b | [510..520) bn scale |
// [520..530) bn shift | [530..930) attn K | [930..950) attn b |
// [950..1000) attn dw | [1000..1010) attn db
__device__ __forceinline__ void load_stage_w(
    float* w, const float* ck, int ckn, const float* cb,
    const float* g, const float* be, const float* m, const float* v,
    const float* aK, int aKn, const float* ab,
    const float* adw, const float* adb)
{
  const int tid = threadIdx.x;
  for (int i = tid; i < ckn; i += TPB) w[i] = ck[i];
  if (tid < 10) {
    w[500 + tid] = cb[tid];
    float sc = g[tid] * rsqrtf(v[tid] + 1e-3f);
    w[510 + tid] = sc;
    w[520 + tid] = be[tid] - m[tid] * sc;
    w[1000 + tid] = adb[tid];
  }
  for (int i = tid; i < aKn; i += TPB) w[530 + i] = aK[i];
  if (tid < 20) w[930 + tid] = ab[tid];
  if (tid < 50) w[950 + tid] = adw[tid];
}

// One fused stage on a chunk.
// in  : [(cin*2+h)*SIN + t], t in [0, Lo+4)
// out : [(c*2+o)*SOUT + t],  t in [0, Lo)
// Phase A stages the MHRSSA einsum m[i][o][t] (t in [0, Lo+4)) in LDS once;
// phase B consumes it for depthwise+softmax and fuses conv+BN+lrelu+mul.
template <int CIN, int SIN, int SOUT>
__device__ __forceinline__ void run_stage(
    const float* __restrict__ in, float* __restrict__ out,
    float* __restrict__ mbuf, int Lo, const float* __restrict__ w)
{
  const float* ck    = w;
  const float* cb    = w + 500;
  const float* scale = w + 510;
  const float* shift = w + 520;
  const float* aK    = w + 530;
  const float* ab    = w + 930;
  const float* adw   = w + 950;
  const float* adb   = w + 1000;
  const int Li = Lo + 4;

  // ---- Phase A: m[i][o][t] -> mbuf
  for (int idx = threadIdx.x; idx < 2 * Li; idx += TPB) {
    const int o = (idx >= Li) ? 1 : 0;
    const int t = idx - o * Li;
    float xv[2][CIN];
#pragma unroll
    for (int h = 0; h < 2; ++h)
#pragma unroll
      for (int ci = 0; ci < CIN; ++ci)
        xv[h][ci] = in[(ci * 2 + h) * SIN + t];
#pragma unroll
    for (int i = 0; i < 10; ++i) {
      float acc = ab[i * 2 + o];
#pragma unroll
      for (int h = 0; h < 2; ++h)
#pragma unroll
        for (int ci = 0; ci < CIN; ++ci)
          acc += xv[h][ci] * aK[((i * 2 + h) * CIN + ci) * 2 + o];
      mbuf[(i * 2 + o) * SM + t] = acc;
    }
  }
  __syncthreads();

  // ---- Phase B: depthwise + softmax + conv + bn + lrelu + mul
  for (int idx = threadIdx.x; idx < 2 * Lo; idx += TPB) {
    const int o = (idx >= Lo) ? 1 : 0;
    const int t = idx - o * Lo;

    float y[10];
#pragma unroll
    for (int i = 0; i < 10; ++i) y[i] = adb[i];
#pragma unroll
    for (int wk = 0; wk < 5; ++wk)
#pragma unroll
      for (int i = 0; i < 10; ++i)
        y[i] += mbuf[(i * 2 + o) * SM + t + wk] * adw[wk * 10 + i];

    float cv[10];
#pragma unroll
    for (int c = 0; c < 10; ++c) cv[c] = cb[c];
#pragma unroll
    for (int wk = 0; wk < 5; ++wk)
#pragma unroll
      for (int ci = 0; ci < CIN; ++ci) {
        const float xin = in[(ci * 2 + o) * SIN + t + wk];
#pragma unroll
        for (int c = 0; c < 10; ++c)
          cv[c] += xin * ck[(wk * CIN + ci) * 10 + c];
      }

    float mx = y[0];
#pragma unroll
    for (int i = 1; i < 10; ++i) mx = fmaxf(mx, y[i]);
    float e[10], sm = 0.f;
#pragma unroll
    for (int i = 0; i < 10; ++i) { e[i] = __expf(y[i] - mx); sm += e[i]; }
    const float inv = 1.0f / sm;

#pragma unroll
    for (int c = 0; c < 10; ++c) {
      float bnv = cv[c] * scale[c] + shift[c];
      bnv = (bnv >= 0.f) ? bnv : 0.2f * bnv;
      out[(c * 2 + o) * SOUT + t] = bnv * e[c] * inv;
    }
  }
  __syncthreads();
}

__global__ __launch_bounds__(TPB, 4) void vignet_kernel(
    const float* __restrict__ x,
    const float* __restrict__ c1k, const float* __restrict__ c1b,
    const float* __restrict__ c2k, const float* __restrict__ c2b,
    const float* __restrict__ c3k, const float* __restrict__ c3b,
    const float* __restrict__ c4k, const float* __restrict__ c4b,
    const float* __restrict__ g1, const float* __restrict__ be1,
    const float* __restrict__ m1, const float* __restrict__ v1,
    const float* __restrict__ g2, const float* __restrict__ be2,
    const float* __restrict__ m2, const float* __restrict__ v2,
    const float* __restrict__ g3, const float* __restrict__ be3,
    const float* __restrict__ m3, const float* __restrict__ v3,
    const float* __restrict__ dnsw,
    const float* __restrict__ a1K, const float* __restrict__ a1b,
    const float* __restrict__ a1dw, const float* __restrict__ a1db,
    const float* __restrict__ a2K, const float* __restrict__ a2b,
    const float* __restrict__ a2dw, const float* __restrict__ a2db,
    const float* __restrict__ a3K, const float* __restrict__ a3b,
    const float* __restrict__ a3dw, const float* __restrict__ a3db,
    float* __restrict__ ws)
{
  __shared__ float xbuf[2 * SX];
  __shared__ float bufA[20 * S1];   // h1, then h3
  __shared__ float bufB[20 * S2];   // h2
  __shared__ float mbuf[20 * SM];
  __shared__ float wbuf[1024];
  __shared__ float red[4];

  const int b     = blockIdx.x / NCH;
  const int chunk = blockIdx.x - b * NCH;
  const int base  = chunk * TC;
  const int tc    = min(TC, 988 - base);
  const int tid   = threadIdx.x;

  // x chunk -> xbuf[h*SX + t], t in [0, tc+12)
  const int Lx = tc + 12;
  for (int idx = tid; idx < 2 * Lx; idx += TPB) {
    const int h = (idx >= Lx) ? 1 : 0;
    const int t = idx - h * Lx;
    xbuf[h * SX + t] = x[b * 2000 + h * 1000 + base + t];
  }
  load_stage_w(wbuf, c1k, 50, c1b, g1, be1, m1, v1, a1K, 40, a1b, a1dw, a1db);
  __syncthreads();

  run_stage<1, SX, S1>(xbuf, bufA, mbuf, tc + 8, wbuf);   // h1 -> bufA
  load_stage_w(wbuf, c2k, 500, c2b, g2, be2, m2, v2, a2K, 400, a2b, a2dw, a2db);
  __syncthreads();

  run_stage<10, S1, S2>(bufA, bufB, mbuf, tc + 4, wbuf);  // h2 -> bufB
  load_stage_w(wbuf, c3k, 500, c3b, g3, be3, m3, v3, a3K, 400, a3b, a3dw, a3db);
  __syncthreads();

  run_stage<10, S2, S3>(bufB, bufA, mbuf, tc, wbuf);      // h3 -> bufA

  // stage4 weights: c4k -> [0..400), c4b -> [400..420)
  for (int i = tid; i < 400; i += TPB) wbuf[i] = c4k[i];
  if (tid < 20) wbuf[400 + tid] = c4b[tid];
  __syncthreads();

  // conv4 (2,1) -> lrelu -> dot with dns_w slice. Split the 20 output
  // channels across two thread halves so all 256 threads work at tc=128.
  float partial = 0.f;
  for (int idx = tid; idx < 2 * tc; idx += TPB) {
    const int half = (idx >= tc) ? 1 : 0;
    const int t    = idx - half * tc;
    float xv[2][10];
#pragma unroll
    for (int h = 0; h < 2; ++h)
#pragma unroll
      for (int ci = 0; ci < 10; ++ci)
        xv[h][ci] = bufA[(ci * 2 + h) * S3 + t];
    const float* dwp = dnsw + (base + t) * 20 + half * 10;
    float dot = 0.f;
#pragma unroll
    for (int cc = 0; cc < 10; ++cc) {
      const int ccg = half * 10 + cc;
      float acc = wbuf[400 + ccg];
#pragma unroll
      for (int h = 0; h < 2; ++h)
#pragma unroll
        for (int ci = 0; ci < 10; ++ci)
          acc += xv[h][ci] * wbuf[(h * 10 + ci) * 20 + ccg];
      acc = (acc >= 0.f) ? acc : 0.2f * acc;
      dot += acc * dwp[cc];
    }
    partial += dot;
  }

#pragma unroll
  for (int off = 32; off > 0; off >>= 1)
    partial += __shfl_down(partial, off, 64);
  if ((tid & 63) == 0) red[tid >> 6] = partial;
  __syncthreads();
  if (tid == 0)
    ws[b * NCH + chunk] = red[0] + red[1] + red[2] + red[3];
}

__global__ void vignet_reduce(const float* __restrict__ ws,
                              const float* __restrict__ dnsb,
                              float* __restrict__ out, int B)
{
  const int b = blockIdx.x * blockDim.x + threadIdx.x;
  if (b < B) {
    float s = dnsb[0];
#pragma unroll
    for (int c = 0; c < NCH; ++c) s += ws[b * NCH + c];
    out[b] = s;
  }
}

extern "C" void kernel_launch(void* const* d_in, const int* in_sizes, int n_in,
                              void* d_out, int out_size, void* d_ws, size_t ws_size,
                              hipStream_t stream) {
  const float* p[35];
  for (int i = 0; i < 35; ++i) p[i] = (const float*)d_in[i];
  const int B = in_sizes[0] / 2000;
  float* ws = (float*)d_ws;

  vignet_kernel<<<dim3(B * NCH), dim3(TPB), 0, stream>>>(
      p[0],
      p[1], p[2], p[3], p[4], p[5], p[6], p[7], p[8],
      p[9], p[10], p[11], p[12],
      p[13], p[14], p[15], p[16],
      p[17], p[18], p[19], p[20],
      p[21],                      // dns_w
      p[23], p[24], p[25], p[26],
      p[27], p[28], p[29], p[30],
      p[31], p[32], p[33], p[34],
      ws);

  vignet_reduce<<<dim3((B + TPB - 1) / TPB), dim3(TPB), 0, stream>>>(
      ws, p[22], (float*)d_out, B);
}

// Round 3
// 2468.377 us; speedup vs baseline: 1.1193x; 1.1193x over previous
//
#include <hip/hip_runtime.h>

#define TPB 256
#define TC  128          // h3 output positions per chunk
#define NCH 8            // ceil(988 / TC)

// compile-time LDS strides (max lengths at tc=128)
#define SX 140           // x chunk length  (tc+12)
#define S1 136           // h1 length       (tc+8)
#define S2 132           // h2 length       (tc+4)
#define S3 128           // h3 length       (tc)
#define SM 140           // m buffer length (stage Lo+4, max = tc+12)

// wbuf layout: [0..500) conv k | [500..510) conv b | [510..520) bn scale |
// [520..530) bn shift | [530..930) attn K | [930..950) attn b |
// [950..1000) attn dw | [1000..1010) attn db
__device__ __forceinline__ void load_stage_w(
    float* w, const float* ck, int ckn, const float* cb,
    const float* g, const float* be, const float* m, const float* v,
    const float* aK, int aKn, const float* ab,
    const float* adw, const float* adb)
{
  const int tid = threadIdx.x;
  for (int i = tid; i < ckn; i += TPB) w[i] = ck[i];
  if (tid < 10) {
    w[500 + tid] = cb[tid];
    float sc = g[tid] * rsqrtf(v[tid] + 1e-3f);
    w[510 + tid] = sc;
    w[520 + tid] = be[tid] - m[tid] * sc;
    w[1000 + tid] = adb[tid];
  }
  for (int i = tid; i < aKn; i += TPB) w[530 + i] = aK[i];
  if (tid < 20) w[930 + tid] = ab[tid];
  if (tid < 50) w[950 + tid] = adw[tid];
}

// One fused stage on a chunk.
// in  : [(cin*2+h)*SIN + t], t in [0, Lo+4)
// out : [(c*2+o)*SOUT + t],  t in [0, Lo)
// Phase A stages the MHRSSA einsum m[i][o][t] (t in [0, Lo+4)) in LDS once;
// phase B consumes it for depthwise+softmax and fuses conv+BN+lrelu+mul.
template <int CIN, int SIN, int SOUT>
__device__ __forceinline__ void run_stage(
    const float* __restrict__ in, float* __restrict__ out,
    float* __restrict__ mbuf, int Lo, const float* __restrict__ w)
{
  const float* ck    = w;
  const float* cb    = w + 500;
  const float* scale = w + 510;
  const float* shift = w + 520;
  const float* aK    = w + 530;
  const float* ab    = w + 930;
  const float* adw   = w + 950;
  const float* adb   = w + 1000;
  const int Li = Lo + 4;

  // ---- Phase A: m[i][o][t] -> mbuf
  for (int idx = threadIdx.x; idx < 2 * Li; idx += TPB) {
    const int o = (idx >= Li) ? 1 : 0;
    const int t = idx - o * Li;
    float xv[2][CIN];
#pragma unroll
    for (int h = 0; h < 2; ++h)
#pragma unroll
      for (int ci = 0; ci < CIN; ++ci)
        xv[h][ci] = in[(ci * 2 + h) * SIN + t];
#pragma unroll
    for (int i = 0; i < 10; ++i) {
      float acc = ab[i * 2 + o];
#pragma unroll
      for (int h = 0; h < 2; ++h)
#pragma unroll
        for (int ci = 0; ci < CIN; ++ci)
          acc += xv[h][ci] * aK[((i * 2 + h) * CIN + ci) * 2 + o];
      mbuf[(i * 2 + o) * SM + t] = acc;
    }
  }
  __syncthreads();

  // ---- Phase B: depthwise + softmax + conv + bn + lrelu + mul
  for (int idx = threadIdx.x; idx < 2 * Lo; idx += TPB) {
    const int o = (idx >= Lo) ? 1 : 0;
    const int t = idx - o * Lo;

    float y[10];
#pragma unroll
    for (int i = 0; i < 10; ++i) y[i] = adb[i];
#pragma unroll
    for (int wk = 0; wk < 5; ++wk)
#pragma unroll
      for (int i = 0; i < 10; ++i)
        y[i] += mbuf[(i * 2 + o) * SM + t + wk] * adw[wk * 10 + i];

    float cv[10];
#pragma unroll
    for (int c = 0; c < 10; ++c) cv[c] = cb[c];
#pragma unroll
    for (int wk = 0; wk < 5; ++wk)
#pragma unroll
      for (int ci = 0; ci < CIN; ++ci) {
        const float xin = in[(ci * 2 + o) * SIN + t + wk];
#pragma unroll
        for (int c = 0; c < 10; ++c)
          cv[c] += xin * ck[(wk * CIN + ci) * 10 + c];
      }

    float mx = y[0];
#pragma unroll
    for (int i = 1; i < 10; ++i) mx = fmaxf(mx, y[i]);
    float e[10], sm = 0.f;
#pragma unroll
    for (int i = 0; i < 10; ++i) { e[i] = __expf(y[i] - mx); sm += e[i]; }
    const float inv = 1.0f / sm;

#pragma unroll
    for (int c = 0; c < 10; ++c) {
      float bnv = cv[c] * scale[c] + shift[c];
      bnv = (bnv >= 0.f) ? bnv : 0.2f * bnv;
      out[(c * 2 + o) * SOUT + t] = bnv * e[c] * inv;
    }
  }
  __syncthreads();
}

// min 3 waves/EU -> VGPR cap ~170: fits Phase B's ~100-reg live set with no
// spill (round 2's (256,4) forced 64 VGPRs -> 8.7 GB scratch traffic).
__global__ __launch_bounds__(TPB, 3) void vignet_kernel(
    const float* __restrict__ x,
    const float* __restrict__ c1k, const float* __restrict__ c1b,
    const float* __restrict__ c2k, const float* __restrict__ c2b,
    const float* __restrict__ c3k, const float* __restrict__ c3b,
    const float* __restrict__ c4k, const float* __restrict__ c4b,
    const float* __restrict__ g1, const float* __restrict__ be1,
    const float* __restrict__ m1, const float* __restrict__ v1,
    const float* __restrict__ g2, const float* __restrict__ be2,
    const float* __restrict__ m2, const float* __restrict__ v2,
    const float* __restrict__ g3, const float* __restrict__ be3,
    const float* __restrict__ m3, const float* __restrict__ v3,
    const float* __restrict__ dnsw,
    const float* __restrict__ a1K, const float* __restrict__ a1b,
    const float* __restrict__ a1dw, const float* __restrict__ a1db,
    const float* __restrict__ a2K, const float* __restrict__ a2b,
    const float* __restrict__ a2dw, const float* __restrict__ a2db,
    const float* __restrict__ a3K, const float* __restrict__ a3b,
    const float* __restrict__ a3dw, const float* __restrict__ a3db,
    float* __restrict__ ws)
{
  __shared__ float xbuf[2 * SX];
  __shared__ float bufA[20 * S1];   // h1, then h3
  __shared__ float bufB[20 * S2];   // h2
  __shared__ float mbuf[20 * SM];
  __shared__ float wbuf[1024];
  __shared__ float red[4];

  const int b     = blockIdx.x / NCH;
  const int chunk = blockIdx.x - b * NCH;
  const int base  = chunk * TC;
  const int tc    = min(TC, 988 - base);
  const int tid   = threadIdx.x;

  // x chunk -> xbuf[h*SX + t], t in [0, tc+12)
  const int Lx = tc + 12;
  for (int idx = tid; idx < 2 * Lx; idx += TPB) {
    const int h = (idx >= Lx) ? 1 : 0;
    const int t = idx - h * Lx;
    xbuf[h * SX + t] = x[b * 2000 + h * 1000 + base + t];
  }
  load_stage_w(wbuf, c1k, 50, c1b, g1, be1, m1, v1, a1K, 40, a1b, a1dw, a1db);
  __syncthreads();

  run_stage<1, SX, S1>(xbuf, bufA, mbuf, tc + 8, wbuf);   // h1 -> bufA
  load_stage_w(wbuf, c2k, 500, c2b, g2, be2, m2, v2, a2K, 400, a2b, a2dw, a2db);
  __syncthreads();

  run_stage<10, S1, S2>(bufA, bufB, mbuf, tc + 4, wbuf);  // h2 -> bufB
  load_stage_w(wbuf, c3k, 500, c3b, g3, be3, m3, v3, a3K, 400, a3b, a3dw, a3db);
  __syncthreads();

  run_stage<10, S2, S3>(bufB, bufA, mbuf, tc, wbuf);      // h3 -> bufA

  // stage4 weights: c4k -> [0..400), c4b -> [400..420)
  for (int i = tid; i < 400; i += TPB) wbuf[i] = c4k[i];
  if (tid < 20) wbuf[400 + tid] = c4b[tid];
  __syncthreads();

  // conv4 (2,1) -> lrelu -> dot with dns_w slice. Split the 20 output
  // channels across two thread halves so all 256 threads work at tc=128.
  float partial = 0.f;
  for (int idx = tid; idx < 2 * tc; idx += TPB) {
    const int half = (idx >= tc) ? 1 : 0;
    const int t    = idx - half * tc;
    float xv[2][10];
#pragma unroll
    for (int h = 0; h < 2; ++h)
#pragma unroll
      for (int ci = 0; ci < 10; ++ci)
        xv[h][ci] = bufA[(ci * 2 + h) * S3 + t];
    const float* dwp = dnsw + (base + t) * 20 + half * 10;
    float dot = 0.f;
#pragma unroll
    for (int cc = 0; cc < 10; ++cc) {
      const int ccg = half * 10 + cc;
      float acc = wbuf[400 + ccg];
#pragma unroll
      for (int h = 0; h < 2; ++h)
#pragma unroll
        for (int ci = 0; ci < 10; ++ci)
          acc += xv[h][ci] * wbuf[(h * 10 + ci) * 20 + ccg];
      acc = (acc >= 0.f) ? acc : 0.2f * acc;
      dot += acc * dwp[cc];
    }
    partial += dot;
  }

#pragma unroll
  for (int off = 32; off > 0; off >>= 1)
    partial += __shfl_down(partial, off, 64);
  if ((tid & 63) == 0) red[tid >> 6] = partial;
  __syncthreads();
  if (tid == 0)
    ws[b * NCH + chunk] = red[0] + red[1] + red[2] + red[3];
}

__global__ void vignet_reduce(const float* __restrict__ ws,
                              const float* __restrict__ dnsb,
                              float* __restrict__ out, int B)
{
  const int b = blockIdx.x * blockDim.x + threadIdx.x;
  if (b < B) {
    float s = dnsb[0];
#pragma unroll
    for (int c = 0; c < NCH; ++c) s += ws[b * NCH + c];
    out[b] = s;
  }
}

extern "C" void kernel_launch(void* const* d_in, const int* in_sizes, int n_in,
                              void* d_out, int out_size, void* d_ws, size_t ws_size,
                              hipStream_t stream) {
  const float* p[35];
  for (int i = 0; i < 35; ++i) p[i] = (const float*)d_in[i];
  const int B = in_sizes[0] / 2000;
  float* ws = (float*)d_ws;

  vignet_kernel<<<dim3(B * NCH), dim3(TPB), 0, stream>>>(
      p[0],
      p[1], p[2], p[3], p[4], p[5], p[6], p[7], p[8],
      p[9], p[10], p[11], p[12],
      p[13], p[14], p[15], p[16],
      p[17], p[18], p[19], p[20],
      p[21],                      // dns_w
      p[23], p[24], p[25], p[26],
      p[27], p[28], p[29], p[30],
      p[31], p[32], p[33], p[34],
      ws);

  vignet_reduce<<<dim3((B + TPB - 1) / TPB), dim3(TPB), 0, stream>>>(
      ws, p[22], (float*)d_out, B);
}

// Round 4
// 2075.252 us; speedup vs baseline: 1.3314x; 1.1894x over previous
//
#include <hip/hip_runtime.h>

#define TPB 256
#define TC  128          // h3 output positions per chunk
#define NCH 8            // ceil(988 / TC)

// compile-time LDS strides (max lengths at tc=128)
#define SX 140           // x chunk length  (tc+12)
#define S1 136           // h1 length       (tc+8)
#define S2 132           // h2 length       (tc+4)
#define S3 128           // h3 length       (tc)
#define SM 140           // m buffer length (stage Lo+4, max = tc+12)

// wbuf layout: [0..500) conv k | [500..510) conv b | [510..520) bn scale |
// [520..530) bn shift | [530..930) attn K | [930..950) attn b |
// [950..1000) attn dw | [1000..1010) attn db
__device__ __forceinline__ void load_stage_w(
    float* w, const float* ck, int ckn, const float* cb,
    const float* g, const float* be, const float* m, const float* v,
    const float* aK, int aKn, const float* ab,
    const float* adw, const float* adb)
{
  const int tid = threadIdx.x;
  for (int i = tid; i < ckn; i += TPB) w[i] = ck[i];
  if (tid < 10) {
    w[500 + tid] = cb[tid];
    float sc = g[tid] * rsqrtf(v[tid] + 1e-3f);
    w[510 + tid] = sc;
    w[520 + tid] = be[tid] - m[tid] * sc;
    w[1000 + tid] = adb[tid];
  }
  for (int i = tid; i < aKn; i += TPB) w[530 + i] = aK[i];
  if (tid < 20) w[930 + tid] = ab[tid];
  if (tid < 50) w[950 + tid] = adw[tid];
}

// One fused stage on a chunk, channel-split so per-thread state stays tiny
// (round 1-3 kept 10-channel arrays per thread -> failed alloca promotion ->
// GBs of scratch traffic; this version holds at most 5-element arrays).
// in  : [(cin*2+h)*SIN + t]; out : [(c*2+o)*SOUT + t]
template <int CIN, int SIN, int SOUT>
__device__ __forceinline__ void run_stage(
    const float* __restrict__ in, float* __restrict__ out,
    float* __restrict__ mbuf, int Lo, const float* __restrict__ w)
{
  const float* ck    = w;
  const float* cb    = w + 500;
  const float* scale = w + 510;
  const float* shift = w + 520;
  const float* aK    = w + 530;
  const float* ab    = w + 930;
  const float* adw   = w + 950;
  const float* adb   = w + 1000;
  const int Li = Lo + 4;

  // ---- Phase A: m[i][o][t] -> mbuf. thread = (head-half, o, t); scalar acc.
#pragma unroll 1
  for (int idx = threadIdx.x; idx < 4 * Li; idx += TPB) {
    const int ih = idx & 1;            // head half: i in [ih*5, ih*5+5)
    const int o  = (idx >> 1) & 1;
    const int t  = idx >> 2;
    float xv[2][CIN];
#pragma unroll
    for (int h = 0; h < 2; ++h)
#pragma unroll
      for (int ci = 0; ci < CIN; ++ci)
        xv[h][ci] = in[(ci * 2 + h) * SIN + t];
#pragma unroll
    for (int j = 0; j < 5; ++j) {
      const int i = ih * 5 + j;
      float acc = ab[i * 2 + o];
#pragma unroll
      for (int h = 0; h < 2; ++h)
#pragma unroll
        for (int ci = 0; ci < CIN; ++ci)
          acc += xv[h][ci] * aK[((i * 2 + h) * CIN + ci) * 2 + o];
      mbuf[(i * 2 + o) * SM + t] = acc;
    }
  }
  __syncthreads();

  // ---- Phase B: thread = (channel-half, o, t); 5 channels per thread,
  // softmax combined across the adjacent-lane pair via shfl_xor(1).
#pragma unroll 1
  for (int idx = threadIdx.x; idx < 4 * Lo; idx += TPB) {
    const int half = idx & 1;          // channels c in [half*5, half*5+5)
    const int o    = (idx >> 1) & 1;
    const int t    = idx >> 2;
    const int c0   = half * 5;

    // depthwise attention logits for this half
    float y[5];
#pragma unroll
    for (int j = 0; j < 5; ++j) y[j] = adb[c0 + j];
#pragma unroll
    for (int wk = 0; wk < 5; ++wk)
#pragma unroll
      for (int j = 0; j < 5; ++j)
        y[j] += mbuf[((c0 + j) * 2 + o) * SM + t + wk] * adw[wk * 10 + c0 + j];

    // conv (1,5) valid, CIN -> 5 channels
    float cv[5];
#pragma unroll
    for (int j = 0; j < 5; ++j) cv[j] = cb[c0 + j];
#pragma unroll
    for (int wk = 0; wk < 5; ++wk)
#pragma unroll
      for (int ci = 0; ci < CIN; ++ci) {
        const float xin = in[(ci * 2 + o) * SIN + t + wk];
#pragma unroll
        for (int j = 0; j < 5; ++j)
          cv[j] += xin * ck[(wk * CIN + ci) * 10 + c0 + j];
      }

    // softmax over 10 heads: pairwise exchange of max and sum
    float mx = y[0];
#pragma unroll
    for (int j = 1; j < 5; ++j) mx = fmaxf(mx, y[j]);
    mx = fmaxf(mx, __shfl_xor(mx, 1, 64));
    float e[5], sm = 0.f;
#pragma unroll
    for (int j = 0; j < 5; ++j) { e[j] = __expf(y[j] - mx); sm += e[j]; }
    sm += __shfl_xor(sm, 1, 64);
    const float inv = 1.0f / sm;

#pragma unroll
    for (int j = 0; j < 5; ++j) {
      float bnv = cv[j] * scale[c0 + j] + shift[c0 + j];
      bnv = (bnv >= 0.f) ? bnv : 0.2f * bnv;
      out[((c0 + j) * 2 + o) * SOUT + t] = bnv * e[j] * inv;
    }
  }
  __syncthreads();
}

__global__ __launch_bounds__(TPB, 3) void vignet_kernel(
    const float* __restrict__ x,
    const float* __restrict__ c1k, const float* __restrict__ c1b,
    const float* __restrict__ c2k, const float* __restrict__ c2b,
    const float* __restrict__ c3k, const float* __restrict__ c3b,
    const float* __restrict__ c4k, const float* __restrict__ c4b,
    const float* __restrict__ g1, const float* __restrict__ be1,
    const float* __restrict__ m1, const float* __restrict__ v1,
    const float* __restrict__ g2, const float* __restrict__ be2,
    const float* __restrict__ m2, const float* __restrict__ v2,
    const float* __restrict__ g3, const float* __restrict__ be3,
    const float* __restrict__ m3, const float* __restrict__ v3,
    const float* __restrict__ dnsw,
    const float* __restrict__ a1K, const float* __restrict__ a1b,
    const float* __restrict__ a1dw, const float* __restrict__ a1db,
    const float* __restrict__ a2K, const float* __restrict__ a2b,
    const float* __restrict__ a2dw, const float* __restrict__ a2db,
    const float* __restrict__ a3K, const float* __restrict__ a3b,
    const float* __restrict__ a3dw, const float* __restrict__ a3db,
    float* __restrict__ ws)
{
  __shared__ float xbuf[2 * SX];
  __shared__ float bufA[20 * S1];   // h1, then h3
  __shared__ float bufB[20 * S2];   // h2
  __shared__ float mbuf[20 * SM];
  __shared__ float wbuf[1024];
  __shared__ float red[4];

  const int b     = blockIdx.x / NCH;
  const int chunk = blockIdx.x - b * NCH;
  const int base  = chunk * TC;
  const int tc    = min(TC, 988 - base);
  const int tid   = threadIdx.x;

  // x chunk -> xbuf[h*SX + t], t in [0, tc+12)
  const int Lx = tc + 12;
  for (int idx = tid; idx < 2 * Lx; idx += TPB) {
    const int h = (idx >= Lx) ? 1 : 0;
    const int t = idx - h * Lx;
    xbuf[h * SX + t] = x[b * 2000 + h * 1000 + base + t];
  }
  load_stage_w(wbuf, c1k, 50, c1b, g1, be1, m1, v1, a1K, 40, a1b, a1dw, a1db);
  __syncthreads();

  run_stage<1, SX, S1>(xbuf, bufA, mbuf, tc + 8, wbuf);   // h1 -> bufA
  load_stage_w(wbuf, c2k, 500, c2b, g2, be2, m2, v2, a2K, 400, a2b, a2dw, a2db);
  __syncthreads();

  run_stage<10, S1, S2>(bufA, bufB, mbuf, tc + 4, wbuf);  // h2 -> bufB
  load_stage_w(wbuf, c3k, 500, c3b, g3, be3, m3, v3, a3K, 400, a3b, a3dw, a3db);
  __syncthreads();

  run_stage<10, S2, S3>(bufB, bufA, mbuf, tc, wbuf);      // h3 -> bufA

  // stage4 weights: c4k -> [0..400), c4b -> [400..420)
  for (int i = tid; i < 400; i += TPB) wbuf[i] = c4k[i];
  if (tid < 20) wbuf[400 + tid] = c4b[tid];
  __syncthreads();

  // conv4 (2,1) -> lrelu -> dot with dns_w slice; 10 channels per thread,
  // two thread-halves cover the 20 output channels.
  float partial = 0.f;
#pragma unroll 1
  for (int idx = tid; idx < 2 * tc; idx += TPB) {
    const int half = (idx >= tc) ? 1 : 0;
    const int t    = idx - half * tc;
    const float* dwp = dnsw + (base + t) * 20 + half * 10;
    float dot = 0.f;
#pragma unroll
    for (int cc = 0; cc < 10; ++cc) {
      const int ccg = half * 10 + cc;
      float acc = wbuf[400 + ccg];
#pragma unroll
      for (int h = 0; h < 2; ++h)
#pragma unroll
        for (int ci = 0; ci < 10; ++ci)
          acc += bufA[(ci * 2 + h) * S3 + t] * wbuf[(h * 10 + ci) * 20 + ccg];
      acc = (acc >= 0.f) ? acc : 0.2f * acc;
      dot += acc * dwp[cc];
    }
    partial += dot;
  }

#pragma unroll
  for (int off = 32; off > 0; off >>= 1)
    partial += __shfl_down(partial, off, 64);
  if ((tid & 63) == 0) red[tid >> 6] = partial;
  __syncthreads();
  if (tid == 0)
    ws[b * NCH + chunk] = red[0] + red[1] + red[2] + red[3];
}

__global__ void vignet_reduce(const float* __restrict__ ws,
                              const float* __restrict__ dnsb,
                              float* __restrict__ out, int B)
{
  const int b = blockIdx.x * blockDim.x + threadIdx.x;
  if (b < B) {
    float s = dnsb[0];
#pragma unroll
    for (int c = 0; c < NCH; ++c) s += ws[b * NCH + c];
    out[b] = s;
  }
}

extern "C" void kernel_launch(void* const* d_in, const int* in_sizes, int n_in,
                              void* d_out, int out_size, void* d_ws, size_t ws_size,
                              hipStream_t stream) {
  const float* p[35];
  for (int i = 0; i < 35; ++i) p[i] = (const float*)d_in[i];
  const int B = in_sizes[0] / 2000;
  float* ws = (float*)d_ws;

  vignet_kernel<<<dim3(B * NCH), dim3(TPB), 0, stream>>>(
      p[0],
      p[1], p[2], p[3], p[4], p[5], p[6], p[7], p[8],
      p[9], p[10], p[11], p[12],
      p[13], p[14], p[15], p[16],
      p[17], p[18], p[19], p[20],
      p[21],                      // dns_w
      p[23], p[24], p[25], p[26],
      p[27], p[28], p[29], p[30],
      p[31], p[32], p[33], p[34],
      ws);

  vignet_reduce<<<dim3((B + TPB - 1) / TPB), dim3(TPB), 0, stream>>>(
      ws, p[22], (float*)d_out, B);
}